// Round 15
// baseline (254.665 us; speedup 1.0000x reference)
//
#include <hip/hip_runtime.h>
#include <hip/hip_bf16.h>

// Problem constants (B=2, P=2048, D=768, H=12, hd=64)
#define B_  2
#define P_  2048
#define D_  768
#define H_  12
#define HD_ 64
#define M_  (B_ * P_)   // 4096
#define N1_ (3 * D_)    // 2304

typedef __attribute__((ext_vector_type(8))) short short8;    // 8 bf16 (4 VGPRs)
typedef __attribute__((ext_vector_type(4))) float f32x4;     // 16x16 MFMA acc
typedef __attribute__((ext_vector_type(16))) float f32x16;   // 32x32 MFMA acc
typedef unsigned short ushort;

__device__ __forceinline__ ushort f2bf(float f) {
    unsigned u = __float_as_uint(f);
    u += 0x7fffu + ((u >> 16) & 1u);   // RNE
    return (ushort)(u >> 16);
}

// q pre-scale: hd^-0.5 / ln2, so attention can use exp2 directly.
#define QSCALE 0.1803368801111243f

// ===========================================================================
// Kernel 0: fp32 -> bf16 elementwise conversion (one-time input casts).
// ===========================================================================
__global__ __launch_bounds__(256) void cvt_bf16(const float* __restrict__ src,
                                                ushort* __restrict__ dst, int n4) {
    int i = blockIdx.x * 256 + threadIdx.x;
    if (i < n4) {
        float4 v = *(const float4*)(src + (size_t)i * 4);
        ushort u4[4] = {f2bf(v.x), f2bf(v.y), f2bf(v.z), f2bf(v.w)};
        *(uint2*)(dst + (size_t)i * 4) = *(uint2*)u4;
    }
}

// ===========================================================================
// Kernel 1: qkv = xb @ wqb (both bf16) + fused per-head QK-LayerNorm.
// 128x128 tile, BK=32, 512 threads / 8 waves (4x2). Staging is now pure
// copies (no converts in the hot loop). Register prefetch.
// ===========================================================================
__global__ __launch_bounds__(512) void gemm_qkv_mfma(
        const ushort* __restrict__ x, const ushort* __restrict__ w,
        const float* __restrict__ qs, const float* __restrict__ qb,
        const float* __restrict__ ks, const float* __restrict__ kb,
        ushort* __restrict__ qkv) {
    __shared__ __align__(16) ushort As[128][40];
    __shared__ __align__(16) ushort Bs[128][40];

    const int tid  = threadIdx.x;
    const int lane = tid & 63;
    const int wv   = tid >> 6;            // 0..7
    const int quad = lane >> 4;
    const int col  = lane & 15;
    const int wr   = (wv >> 1) * 32;
    const int wc   = (wv & 1) * 64;
    const int rowBase = blockIdx.y * 128;
    const int colBase = blockIdx.x * 128;

    const int amr = tid >> 2, ac8 = tid & 3;   // A: 512 uint4 over 128x32 bf16
    const int nB  = tid & 127, kq = tid >> 7;  // B: col nB, k-rows kq*8..+7

    uint4  apre;
    ushort bpre[8];
    auto load_tile = [&](int kt) {
        const int k0 = kt * 32;
        apre = *(const uint4*)(x + (size_t)(rowBase + amr) * D_ + k0 + ac8 * 8);
#pragma unroll
        for (int j = 0; j < 8; j++)
            bpre[j] = w[(size_t)(k0 + kq * 8 + j) * N1_ + colBase + nB];
    };

    f32x4 acc[2][4];
#pragma unroll
    for (int i = 0; i < 2; i++)
#pragma unroll
        for (int j = 0; j < 4; j++) acc[i][j] = (f32x4){0.f, 0.f, 0.f, 0.f};

    load_tile(0);
    const int NT = D_ / 32;
    for (int kt = 0; kt < NT; kt++) {
        __syncthreads();
        *(uint4*)&As[amr][ac8 * 8] = apre;
        *(short8*)&Bs[nB][kq * 8]  = *(short8*)&bpre[0];
        __syncthreads();
        if (kt + 1 < NT) load_tile(kt + 1);

        short8 af[2], bf[4];
#pragma unroll
        for (int mt = 0; mt < 2; mt++) af[mt] = *(const short8*)&As[wr + mt * 16 + col][quad * 8];
#pragma unroll
        for (int nt = 0; nt < 4; nt++) bf[nt] = *(const short8*)&Bs[wc + nt * 16 + col][quad * 8];
#pragma unroll
        for (int mt = 0; mt < 2; mt++)
#pragma unroll
            for (int nt = 0; nt < 4; nt++)
                acc[mt][nt] = __builtin_amdgcn_mfma_f32_16x16x32_bf16(af[mt], bf[nt], acc[mt][nt], 0, 0, 0);
    }

    const int comp = colBase / D_;
    const int rem  = colBase + wc - comp * D_;
    const int h    = rem >> 6;
    float sc4[4] = {0, 0, 0, 0}, bi4[4] = {0, 0, 0, 0};
    if (comp == 0) {
#pragma unroll
        for (int nt = 0; nt < 4; nt++) { sc4[nt] = qs[nt * 16 + col]; bi4[nt] = qb[nt * 16 + col]; }
    } else if (comp == 1) {
#pragma unroll
        for (int nt = 0; nt < 4; nt++) { sc4[nt] = ks[nt * 16 + col]; bi4[nt] = kb[nt * 16 + col]; }
    }

#pragma unroll
    for (int mt = 0; mt < 2; mt++) {
#pragma unroll
        for (int r = 0; r < 4; r++) {
            int m  = rowBase + wr + mt * 16 + quad * 4 + r;
            int bb = m >> 11;
            int p  = m & 2047;
            float v0 = acc[mt][0][r], v1 = acc[mt][1][r], v2 = acc[mt][2][r], v3 = acc[mt][3][r];
            if (comp < 2) {
                float s = v0 + v1 + v2 + v3;
#pragma unroll
                for (int off = 1; off < 16; off <<= 1) s += __shfl_xor(s, off, 64);
                float mean = s * (1.0f / 64.0f);
                float d0 = v0 - mean, d1 = v1 - mean, d2 = v2 - mean, d3 = v3 - mean;
                float sq = d0 * d0 + d1 * d1 + d2 * d2 + d3 * d3;
#pragma unroll
                for (int off = 1; off < 16; off <<= 1) sq += __shfl_xor(sq, off, 64);
                float inv = rsqrtf(sq * (1.0f / 64.0f) + 1e-6f);
                v0 = d0 * inv * sc4[0] + bi4[0];
                v1 = d1 * inv * sc4[1] + bi4[1];
                v2 = d2 * inv * sc4[2] + bi4[2];
                v3 = d3 * inv * sc4[3] + bi4[3];
                if (comp == 0) { v0 *= QSCALE; v1 *= QSCALE; v2 *= QSCALE; v3 *= QSCALE; }
            }
            size_t base = ((((size_t)comp * B_ + bb) * H_ + h) * P_ + p) * HD_;
            qkv[base +  0 + col] = f2bf(v0);
            qkv[base + 16 + col] = f2bf(v1);
            qkv[base + 32 + col] = f2bf(v2);
            qkv[base + 48 + col] = f2bf(v3);
        }
    }
}

// ===========================================================================
// Kernel 2: flash attention, 32x32x16 MFMA, split-K (grid z=2).
// q is pre-scaled by 1/ln2 -> softmax uses bare exp2f. P packed to bf16 by
// TRUNCATION (1 shift); lrow accumulates the truncated value so the
// normalization is self-consistent. Raw partial O written (ln_o normalizes).
// ===========================================================================
__global__ __launch_bounds__(256) void attn_split(const ushort* __restrict__ qkv,
                                                  float* __restrict__ o0,
                                                  float* __restrict__ o1,
                                                  float* __restrict__ l0,
                                                  float* __restrict__ l1) {
    const int p0 = blockIdx.x * 128;
    const int bh = blockIdx.y;
    const int s  = blockIdx.z;
    const int b  = bh / H_, h = bh % H_;
    float* opart = s ? o1 : o0;
    float* lpart = s ? l1 : l0;
    const int tid  = threadIdx.x;
    const int lane = tid & 63;
    const int wv   = tid >> 6;
    const int half = lane >> 5;     // 0/1
    const int n32  = lane & 31;

    __shared__ __align__(16) ushort Ks[64][72];
    __shared__ __align__(16) ushort Vs[64][72];      // [dim][key] transposed
    __shared__ __align__(16) ushort Ps[4][32][72];   // per-wave [q][key]; reused as fp32 [32][36]

    const size_t hs = (size_t)P_ * HD_;
    const ushort* qg = qkv + ((size_t)(0 * B_ + b) * H_ + h) * hs + (size_t)(p0 + wv * 32) * HD_;
    const ushort* kg = qkv + ((size_t)(1 * B_ + b) * H_ + h) * hs + (size_t)s * (P_ / 2) * HD_;
    const ushort* vg = qkv + ((size_t)(2 * B_ + b) * H_ + h) * hs + (size_t)s * (P_ / 2) * HD_;

    // Q A-fragments for 4 K=16 steps, direct from global.
    short8 aq[4];
#pragma unroll
    for (int ks2 = 0; ks2 < 4; ks2++)
        aq[ks2] = *(const short8*)(qg + (size_t)n32 * HD_ + ks2 * 16 + half * 8);

    float lrow[16];
#pragma unroll
    for (int r = 0; r < 16; r++) lrow[r] = 0.f;
    f32x16 oacc[2];
#pragma unroll
    for (int nt = 0; nt < 2; nt++)
#pragma unroll
        for (int r = 0; r < 16; r++) oacc[nt][r] = 0.f;

    const int kr = tid >> 3, kc8 = tid & 7;
    const int vd = tid & 63,  vkh = tid >> 6;

    uint4  kpre[2];
    ushort vpre[16];
    auto load_tile = [&](int kt) {
        const ushort* kg_t = kg + (size_t)kt * 64 * HD_;
        const ushort* vg_t = vg + (size_t)kt * 64 * HD_;
        kpre[0] = *(const uint4*)(kg_t + (size_t)kr * HD_ + kc8 * 8);
        kpre[1] = *(const uint4*)(kg_t + (size_t)(kr + 32) * HD_ + kc8 * 8);
#pragma unroll
        for (int j = 0; j < 16; j++)
            vpre[j] = vg_t[(size_t)(vkh * 16 + j) * HD_ + vd];
    };

    load_tile(0);
    const int NT = (P_ / 2) / 64;    // 16 tiles per split
    for (int kt = 0; kt < NT; kt++) {
        __syncthreads();
        *(uint4*)&Ks[kr][kc8 * 8]      = kpre[0];
        *(uint4*)&Ks[kr + 32][kc8 * 8] = kpre[1];
        *(short8*)&Vs[vd][vkh * 16]     = *(short8*)&vpre[0];
        *(short8*)&Vs[vd][vkh * 16 + 8] = *(short8*)&vpre[8];
        __syncthreads();
        if (kt + 1 < NT) load_tile(kt + 1);

        // S = Q(32x64) @ K^T(64keys x 64): 2 key-tiles x 4 k-steps.
        f32x16 sc[2];
#pragma unroll
        for (int nt = 0; nt < 2; nt++) {
#pragma unroll
            for (int r = 0; r < 16; r++) sc[nt][r] = 0.f;
#pragma unroll
            for (int ks2 = 0; ks2 < 4; ks2++) {
                short8 kb2 = *(const short8*)&Ks[nt * 32 + n32][ks2 * 16 + half * 8];
                sc[nt] = __builtin_amdgcn_mfma_f32_32x32x16_bf16(aq[ks2], kb2, sc[nt], 0, 0, 0);
            }
        }

        // Unnormalized softmax: p = 2^min(s,86) (q pre-scaled by 1/ln2).
        // Truncation pack; lrow accumulates the truncated value.
#pragma unroll
        for (int reg = 0; reg < 16; reg++) {
            int row = (reg & 3) + 8 * (reg >> 2) + 4 * half;
#pragma unroll
            for (int nt = 0; nt < 2; nt++) {
                float p = exp2f(fminf(sc[nt][reg], 86.f));
                unsigned u = __float_as_uint(p);
                lrow[reg] += __uint_as_float(u & 0xffff0000u);
                Ps[wv][row][nt * 32 + n32] = (ushort)(u >> 16);
            }
        }
        // No barrier: Ps is per-wave; DS ops are wave-in-order.

        // O(32q x 64d) += P(32q x 64key) @ V(64key x 64d).
#pragma unroll
        for (int kp = 0; kp < 4; kp++) {
            short8 pa = *(const short8*)&Ps[wv][n32][kp * 16 + half * 8];
#pragma unroll
            for (int nt = 0; nt < 2; nt++) {
                short8 vb = *(const short8*)&Vs[nt * 32 + n32][kp * 16 + half * 8];
                oacc[nt] = __builtin_amdgcn_mfma_f32_32x32x16_bf16(pa, vb, oacc[nt], 0, 0, 0);
            }
        }
    }

    // Row-sum reduction over the 32 cols (lanes within each half).
#pragma unroll
    for (int reg = 0; reg < 16; reg++) {
#pragma unroll
        for (int off = 1; off < 32; off <<= 1)
            lrow[reg] += __shfl_xor(lrow[reg], off, 64);
    }

    // l writes: lane 0 of each half writes its 16 rows.
    if (n32 == 0) {
#pragma unroll
        for (int reg = 0; reg < 16; reg++) {
            int row = (reg & 3) + 8 * (reg >> 2) + 4 * half;
            lpart[(size_t)bh * P_ + p0 + wv * 32 + row] = lrow[reg];
        }
    }

    // RAW partial-O writeback via per-wave LDS transpose (Ps[wv] as [32][36] f32).
    float* Psf = (float*)&Ps[wv][0][0];
#pragma unroll
    for (int nt = 0; nt < 2; nt++) {
#pragma unroll
        for (int reg = 0; reg < 16; reg++) {
            int row = (reg & 3) + 8 * (reg >> 2) + 4 * half;
            Psf[row * 36 + n32] = oacc[nt][reg];
        }
        // In-wave DS ordering: writes above complete before reads below.
#pragma unroll
        for (int i = 0; i < 4; i++) {
            int ql = i * 8 + (lane >> 3);
            int c4 = lane & 7;
            float4 v = *(const float4*)&Psf[ql * 36 + c4 * 4];
            *(float4*)(opart + ((size_t)bh * P_ + p0 + wv * 32 + ql) * HD_ + nt * 32 + c4 * 4) = v;
        }
    }
}

// ===========================================================================
// Kernel 3: LayerNorm over D=768, fused split-combine: v = (o0+o1)/(l0+l1).
// (unchanged — sole owner of normalization)
// ===========================================================================
__global__ __launch_bounds__(256) void ln_o(const float* __restrict__ o0,
                                            const float* __restrict__ o1,
                                            const float* __restrict__ l0,
                                            const float* __restrict__ l1,
                                            ushort* __restrict__ lnb,
                                            const float* __restrict__ osc,
                                            const float* __restrict__ ob) {
    __shared__ float red[4];
    __shared__ float red2[4];
    const int row = blockIdx.x;          // b*P + p
    const int b   = row >> 11;
    const int p   = row & (P_ - 1);
    const int tid = threadIdx.x;

    auto src = [&](int d) {
        int h = d >> 6;
        size_t lr  = (size_t)(b * H_ + h) * P_ + p;
        size_t idx = lr * HD_ + (d & 63);
        return (o0[idx] + o1[idx]) / (l0[lr] + l1[lr]);
    };
    float v0 = src(tid);
    float v1 = src(tid + 256);
    float v2 = src(tid + 512);
    float s = v0 + v1 + v2;
#pragma unroll
    for (int o = 32; o > 0; o >>= 1) s += __shfl_xor(s, o, 64);
    if ((tid & 63) == 0) red[tid >> 6] = s;
    __syncthreads();
    float mean = (red[0] + red[1] + red[2] + red[3]) * (1.0f / 768.0f);
    float d0 = v0 - mean, d1 = v1 - mean, d2 = v2 - mean;
    float sq = d0 * d0 + d1 * d1 + d2 * d2;
#pragma unroll
    for (int o = 32; o > 0; o >>= 1) sq += __shfl_xor(sq, o, 64);
    if ((tid & 63) == 0) red2[tid >> 6] = sq;
    __syncthreads();
    float var = (red2[0] + red2[1] + red2[2] + red2[3]) * (1.0f / 768.0f);
    float inv = rsqrtf(var + 1e-6f);
    const size_t base = (size_t)row * D_;
    lnb[base + tid]       = f2bf(d0 * inv * osc[tid]       + ob[tid]);
    lnb[base + tid + 256] = f2bf(d1 * inv * osc[tid + 256] + ob[tid + 256]);
    lnb[base + tid + 512] = f2bf(d2 * inv * osc[tid + 512] + ob[tid + 512]);
}

// ===========================================================================
// Kernel 4: out = ln_buf(bf16) @ wob(bf16) + b_out. 64x64 tile; staging is
// pure copies (W pre-converted).
// ===========================================================================
__global__ __launch_bounds__(256) void gemm_out_mfma(
        const ushort* __restrict__ a, const ushort* __restrict__ w,
        const float* __restrict__ bias, float* __restrict__ out) {
    __shared__ __align__(16) ushort As[64][40];
    __shared__ __align__(16) ushort Bs[64][40];

    const int tid  = threadIdx.x;
    const int lane = tid & 63;
    const int wv   = tid >> 6;
    const int quad = lane >> 4;
    const int col  = lane & 15;
    const int wr   = (wv >> 1) * 32;
    const int wc   = (wv & 1) * 32;
    const int rowBase = blockIdx.y * 64;
    const int colBase = blockIdx.x * 64;

    const int am  = tid >> 2, ac8 = tid & 3;
    const int nB  = tid & 63, kq = tid >> 6;

    uint4  apre;
    ushort bpre[8];
    auto load_tile = [&](int kt) {
        const int k0 = kt * 32;
        apre = *(const uint4*)(a + (size_t)(rowBase + am) * D_ + k0 + ac8 * 8);
#pragma unroll
        for (int j = 0; j < 8; j++)
            bpre[j] = w[(size_t)(k0 + kq * 8 + j) * D_ + colBase + nB];
    };

    f32x4 acc[2][2];
#pragma unroll
    for (int i = 0; i < 2; i++)
#pragma unroll
        for (int j = 0; j < 2; j++) acc[i][j] = (f32x4){0.f, 0.f, 0.f, 0.f};

    load_tile(0);
    const int NT = D_ / 32;
    for (int kt = 0; kt < NT; kt++) {
        __syncthreads();
        *(uint4*)&As[am][ac8 * 8] = apre;
        *(short8*)&Bs[nB][kq * 8] = *(short8*)&bpre[0];
        __syncthreads();
        if (kt + 1 < NT) load_tile(kt + 1);

        short8 af[2], bf[2];
#pragma unroll
        for (int mt = 0; mt < 2; mt++) af[mt] = *(const short8*)&As[wr + mt * 16 + col][quad * 8];
#pragma unroll
        for (int nt = 0; nt < 2; nt++) bf[nt] = *(const short8*)&Bs[wc + nt * 16 + col][quad * 8];
#pragma unroll
        for (int mt = 0; mt < 2; mt++)
#pragma unroll
            for (int nt = 0; nt < 2; nt++)
                acc[mt][nt] = __builtin_amdgcn_mfma_f32_16x16x32_bf16(af[mt], bf[nt], acc[mt][nt], 0, 0, 0);
    }

    float b2[2];
#pragma unroll
    for (int nt = 0; nt < 2; nt++) b2[nt] = bias[colBase + wc + nt * 16 + col];
#pragma unroll
    for (int mt = 0; mt < 2; mt++) {
#pragma unroll
        for (int r = 0; r < 4; r++) {
            int m = rowBase + wr + mt * 16 + quad * 4 + r;
            float* dst = out + (size_t)m * D_ + colBase + wc;
#pragma unroll
            for (int nt = 0; nt < 2; nt++)
                dst[nt * 16 + col] = acc[mt][nt][r] + b2[nt];
        }
    }
}

// ---------------------------------------------------------------------------
extern "C" void kernel_launch(void* const* d_in, const int* in_sizes, int n_in,
                              void* d_out, int out_size, void* d_ws, size_t ws_size,
                              hipStream_t stream) {
    const float* x    = (const float*)d_in[0];
    const float* Wqkv = (const float*)d_in[1];
    const float* qs   = (const float*)d_in[2];
    const float* qb   = (const float*)d_in[3];
    const float* ks   = (const float*)d_in[4];
    const float* kb   = (const float*)d_in[5];
    const float* osc  = (const float*)d_in[6];
    const float* ob   = (const float*)d_in[7];
    const float* Wout = (const float*)d_in[8];
    const float* bout = (const float*)d_in[9];
    float* out = (float*)d_out;

    // Workspace (33.1 MB): qkv bf16 18.9MB | opart0 fp32 12.6MB | l0,l1 | wob 1.2MB.
    // xb (6.3MB) + wqb (3.5MB) OVERLAY opart0 (dead until attn; gemm_qkv done by then).
    // d_out holds opart1 during attention.
    ushort* qkv    = (ushort*)d_ws;                       // 9,437,184 ushorts
    float*  opart0 = (float*)(qkv + 9437184);             // 3,145,728 floats
    float*  l0     = opart0 + 3145728;                    // 49,152
    float*  l1     = l0 + 49152;                          // 49,152
    ushort* wob    = (ushort*)(l1 + 49152);               // 589,824 ushorts
    ushort* xb     = (ushort*)opart0;                     // overlay: 3,145,728 ushorts
    ushort* wqb    = xb + 3145728;                        // overlay: 1,769,472 ushorts
    float*  opart1 = out;
    ushort* ln_buf = qkv;   // overlays dead q-region after attention

    cvt_bf16<<<dim3(786432 / 256), 256, 0, stream>>>(x, xb, 786432);       // x: 3.1M elems
    cvt_bf16<<<dim3(442368 / 256), 256, 0, stream>>>(Wqkv, wqb, 442368);   // W_qkv: 1.77M
    cvt_bf16<<<dim3(147456 / 256), 256, 0, stream>>>(Wout, wob, 147456);   // W_out: 0.59M

    gemm_qkv_mfma<<<dim3(N1_ / 128, M_ / 128), 512, 0, stream>>>(xb, wqb, qs, qb, ks, kb, qkv);
    attn_split<<<dim3(P_ / 128, B_ * H_, 2), 256, 0, stream>>>(qkv, opart0, opart1, l0, l1);
    ln_o<<<dim3(M_), 256, 0, stream>>>(opart0, opart1, l0, l1, ln_buf, osc, ob);
    gemm_out_mfma<<<dim3(D_ / 64, M_ / 64), 256, 0, stream>>>(ln_buf, wob, bout, out);
}

// Round 16
// 236.738 us; speedup vs baseline: 1.0757x; 1.0757x over previous
//
#include <hip/hip_runtime.h>
#include <hip/hip_bf16.h>

// Problem constants (B=2, P=2048, D=768, H=12, hd=64)
#define B_  2
#define P_  2048
#define D_  768
#define H_  12
#define HD_ 64
#define M_  (B_ * P_)   // 4096
#define N1_ (3 * D_)    // 2304

typedef __attribute__((ext_vector_type(8))) short short8;    // 8 bf16 (4 VGPRs)
typedef __attribute__((ext_vector_type(4))) float f32x4;     // 16x16 MFMA acc
typedef __attribute__((ext_vector_type(16))) float f32x16;   // 32x32 MFMA acc
typedef unsigned short ushort;

__device__ __forceinline__ ushort f2bf(float f) {
    unsigned u = __float_as_uint(f);
    u += 0x7fffu + ((u >> 16) & 1u);   // RNE
    return (ushort)(u >> 16);
}

// q pre-scale: hd^-0.5 / ln2 -> softmax uses bare 2^x.
#define QSCALE 0.1803368801111243f

// Raw v_exp_f32 (single instruction); fallback = native exp (mul + v_exp).
#if __has_builtin(__builtin_amdgcn_exp2f)
#define FAST_EXP2(x) __builtin_amdgcn_exp2f(x)
#else
#define FAST_EXP2(x) __expf((x) * 0.6931471805599453f)
#endif

// ===========================================================================
// Kernel 1: qkv = x @ W_qkv (bf16 MFMA) + fused per-head QK-LayerNorm.
// 128x128 tile, BK=32, 512 threads / 8 waves (4x2). (R14 structure; q-scale
// now folds 1/ln2)
// ===========================================================================
__global__ __launch_bounds__(512) void gemm_qkv_mfma(
        const float* __restrict__ x, const float* __restrict__ w,
        const float* __restrict__ qs, const float* __restrict__ qb,
        const float* __restrict__ ks, const float* __restrict__ kb,
        ushort* __restrict__ qkv) {
    __shared__ __align__(16) ushort As[128][40];
    __shared__ __align__(16) ushort Bs[128][40];

    const int tid  = threadIdx.x;
    const int lane = tid & 63;
    const int wv   = tid >> 6;            // 0..7
    const int quad = lane >> 4;
    const int col  = lane & 15;
    const int wr   = (wv >> 1) * 32;
    const int wc   = (wv & 1) * 64;
    const int rowBase = blockIdx.y * 128;
    const int colBase = blockIdx.x * 128;

    const int am0 = tid >> 3, ac4 = tid & 7;
    const int nB  = tid & 127, kq = tid >> 7;

    float4 apre[2];
    float  bpre[8];
    auto load_tile = [&](int kt) {
        const int k0 = kt * 32;
        apre[0] = *(const float4*)(x + (size_t)(rowBase + am0) * D_ + k0 + ac4 * 4);
        apre[1] = *(const float4*)(x + (size_t)(rowBase + am0 + 64) * D_ + k0 + ac4 * 4);
#pragma unroll
        for (int j = 0; j < 8; j++)
            bpre[j] = w[(size_t)(k0 + kq * 8 + j) * N1_ + colBase + nB];
    };

    f32x4 acc[2][4];
#pragma unroll
    for (int i = 0; i < 2; i++)
#pragma unroll
        for (int j = 0; j < 4; j++) acc[i][j] = (f32x4){0.f, 0.f, 0.f, 0.f};

    load_tile(0);
    const int NT = D_ / 32;
    for (int kt = 0; kt < NT; kt++) {
        __syncthreads();
        {
            ushort u0[4] = {f2bf(apre[0].x), f2bf(apre[0].y), f2bf(apre[0].z), f2bf(apre[0].w)};
            ushort u1[4] = {f2bf(apre[1].x), f2bf(apre[1].y), f2bf(apre[1].z), f2bf(apre[1].w)};
            *(uint2*)&As[am0][ac4 * 4]      = *(uint2*)u0;
            *(uint2*)&As[am0 + 64][ac4 * 4] = *(uint2*)u1;
            ushort us[8];
#pragma unroll
            for (int j = 0; j < 8; j++) us[j] = f2bf(bpre[j]);
            *(short8*)&Bs[nB][kq * 8] = *(short8*)&us[0];
        }
        __syncthreads();
        if (kt + 1 < NT) load_tile(kt + 1);

        short8 af[2], bf[4];
#pragma unroll
        for (int mt = 0; mt < 2; mt++) af[mt] = *(const short8*)&As[wr + mt * 16 + col][quad * 8];
#pragma unroll
        for (int nt = 0; nt < 4; nt++) bf[nt] = *(const short8*)&Bs[wc + nt * 16 + col][quad * 8];
#pragma unroll
        for (int mt = 0; mt < 2; mt++)
#pragma unroll
            for (int nt = 0; nt < 4; nt++)
                acc[mt][nt] = __builtin_amdgcn_mfma_f32_16x16x32_bf16(af[mt], bf[nt], acc[mt][nt], 0, 0, 0);
    }

    const int comp = colBase / D_;
    const int rem  = colBase + wc - comp * D_;
    const int h    = rem >> 6;
    float sc4[4] = {0, 0, 0, 0}, bi4[4] = {0, 0, 0, 0};
    if (comp == 0) {
#pragma unroll
        for (int nt = 0; nt < 4; nt++) { sc4[nt] = qs[nt * 16 + col]; bi4[nt] = qb[nt * 16 + col]; }
    } else if (comp == 1) {
#pragma unroll
        for (int nt = 0; nt < 4; nt++) { sc4[nt] = ks[nt * 16 + col]; bi4[nt] = kb[nt * 16 + col]; }
    }

#pragma unroll
    for (int mt = 0; mt < 2; mt++) {
#pragma unroll
        for (int r = 0; r < 4; r++) {
            int m  = rowBase + wr + mt * 16 + quad * 4 + r;
            int bb = m >> 11;
            int p  = m & 2047;
            float v0 = acc[mt][0][r], v1 = acc[mt][1][r], v2 = acc[mt][2][r], v3 = acc[mt][3][r];
            if (comp < 2) {
                float s = v0 + v1 + v2 + v3;
#pragma unroll
                for (int off = 1; off < 16; off <<= 1) s += __shfl_xor(s, off, 64);
                float mean = s * (1.0f / 64.0f);
                float d0 = v0 - mean, d1 = v1 - mean, d2 = v2 - mean, d3 = v3 - mean;
                float sq = d0 * d0 + d1 * d1 + d2 * d2 + d3 * d3;
#pragma unroll
                for (int off = 1; off < 16; off <<= 1) sq += __shfl_xor(sq, off, 64);
                float inv = rsqrtf(sq * (1.0f / 64.0f) + 1e-6f);
                v0 = d0 * inv * sc4[0] + bi4[0];
                v1 = d1 * inv * sc4[1] + bi4[1];
                v2 = d2 * inv * sc4[2] + bi4[2];
                v3 = d3 * inv * sc4[3] + bi4[3];
                if (comp == 0) { v0 *= QSCALE; v1 *= QSCALE; v2 *= QSCALE; v3 *= QSCALE; }
            }
            size_t base = ((((size_t)comp * B_ + bb) * H_ + h) * P_ + p) * HD_;
            qkv[base +  0 + col] = f2bf(v0);
            qkv[base + 16 + col] = f2bf(v1);
            qkv[base + 32 + col] = f2bf(v2);
            qkv[base + 48 + col] = f2bf(v3);
        }
    }
}

// ===========================================================================
// Kernel 2: flash attention, 32x32x16 MFMA, split-K (grid z=2).
// R14 structure; softmax now p = v_exp(min(s,86)) (q pre-scaled by 1/ln2)
// with truncation pack; lrow accumulates the truncated value.
// ===========================================================================
__global__ __launch_bounds__(256) void attn_split(const ushort* __restrict__ qkv,
                                                  float* __restrict__ o0,
                                                  float* __restrict__ o1,
                                                  float* __restrict__ l0,
                                                  float* __restrict__ l1) {
    const int p0 = blockIdx.x * 128;
    const int bh = blockIdx.y;
    const int s  = blockIdx.z;
    const int b  = bh / H_, h = bh % H_;
    float* opart = s ? o1 : o0;
    float* lpart = s ? l1 : l0;
    const int tid  = threadIdx.x;
    const int lane = tid & 63;
    const int wv   = tid >> 6;
    const int half = lane >> 5;     // 0/1
    const int n32  = lane & 31;

    __shared__ __align__(16) ushort Ks[64][72];
    __shared__ __align__(16) ushort Vs[64][72];      // [dim][key] transposed
    __shared__ __align__(16) ushort Ps[4][32][72];   // per-wave [q][key]; reused as fp32 [32][36]

    const size_t hs = (size_t)P_ * HD_;
    const ushort* qg = qkv + ((size_t)(0 * B_ + b) * H_ + h) * hs + (size_t)(p0 + wv * 32) * HD_;
    const ushort* kg = qkv + ((size_t)(1 * B_ + b) * H_ + h) * hs + (size_t)s * (P_ / 2) * HD_;
    const ushort* vg = qkv + ((size_t)(2 * B_ + b) * H_ + h) * hs + (size_t)s * (P_ / 2) * HD_;

    // Q A-fragments for 4 K=16 steps, direct from global.
    short8 aq[4];
#pragma unroll
    for (int ks2 = 0; ks2 < 4; ks2++)
        aq[ks2] = *(const short8*)(qg + (size_t)n32 * HD_ + ks2 * 16 + half * 8);

    float lrow[16];
#pragma unroll
    for (int r = 0; r < 16; r++) lrow[r] = 0.f;
    f32x16 oacc[2];
#pragma unroll
    for (int nt = 0; nt < 2; nt++)
#pragma unroll
        for (int r = 0; r < 16; r++) oacc[nt][r] = 0.f;

    const int kr = tid >> 3, kc8 = tid & 7;
    const int vd = tid & 63,  vkh = tid >> 6;

    uint4  kpre[2];
    ushort vpre[16];
    auto load_tile = [&](int kt) {
        const ushort* kg_t = kg + (size_t)kt * 64 * HD_;
        const ushort* vg_t = vg + (size_t)kt * 64 * HD_;
        kpre[0] = *(const uint4*)(kg_t + (size_t)kr * HD_ + kc8 * 8);
        kpre[1] = *(const uint4*)(kg_t + (size_t)(kr + 32) * HD_ + kc8 * 8);
#pragma unroll
        for (int j = 0; j < 16; j++)
            vpre[j] = vg_t[(size_t)(vkh * 16 + j) * HD_ + vd];
    };

    load_tile(0);
    const int NT = (P_ / 2) / 64;    // 16 tiles per split
    for (int kt = 0; kt < NT; kt++) {
        __syncthreads();
        *(uint4*)&Ks[kr][kc8 * 8]      = kpre[0];
        *(uint4*)&Ks[kr + 32][kc8 * 8] = kpre[1];
        *(short8*)&Vs[vd][vkh * 16]     = *(short8*)&vpre[0];
        *(short8*)&Vs[vd][vkh * 16 + 8] = *(short8*)&vpre[8];
        __syncthreads();
        if (kt + 1 < NT) load_tile(kt + 1);

        // S = Q(32x64) @ K^T(64keys x 64): 2 key-tiles x 4 k-steps.
        f32x16 sc[2];
#pragma unroll
        for (int nt = 0; nt < 2; nt++) {
#pragma unroll
            for (int r = 0; r < 16; r++) sc[nt][r] = 0.f;
#pragma unroll
            for (int ks2 = 0; ks2 < 4; ks2++) {
                short8 kb2 = *(const short8*)&Ks[nt * 32 + n32][ks2 * 16 + half * 8];
                sc[nt] = __builtin_amdgcn_mfma_f32_32x32x16_bf16(aq[ks2], kb2, sc[nt], 0, 0, 0);
            }
        }

        // Unnormalized softmax: p = 2^min(s,86) via raw v_exp_f32.
        // Truncation pack; lrow accumulates the truncated value.
#pragma unroll
        for (int reg = 0; reg < 16; reg++) {
            int row = (reg & 3) + 8 * (reg >> 2) + 4 * half;
#pragma unroll
            for (int nt = 0; nt < 2; nt++) {
                float p = FAST_EXP2(fminf(sc[nt][reg], 86.f));
                unsigned u = __float_as_uint(p);
                lrow[reg] += __uint_as_float(u & 0xffff0000u);
                Ps[wv][row][nt * 32 + n32] = (ushort)(u >> 16);
            }
        }
        // No barrier: Ps is per-wave; DS ops are wave-in-order.

        // O(32q x 64d) += P(32q x 64key) @ V(64key x 64d).
#pragma unroll
        for (int kp = 0; kp < 4; kp++) {
            short8 pa = *(const short8*)&Ps[wv][n32][kp * 16 + half * 8];
#pragma unroll
            for (int nt = 0; nt < 2; nt++) {
                short8 vb = *(const short8*)&Vs[nt * 32 + n32][kp * 16 + half * 8];
                oacc[nt] = __builtin_amdgcn_mfma_f32_32x32x16_bf16(pa, vb, oacc[nt], 0, 0, 0);
            }
        }
    }

    // Row-sum reduction over the 32 cols (lanes within each half).
#pragma unroll
    for (int reg = 0; reg < 16; reg++) {
#pragma unroll
        for (int off = 1; off < 32; off <<= 1)
            lrow[reg] += __shfl_xor(lrow[reg], off, 64);
    }

    // l writes: lane 0 of each half writes its 16 rows.
    if (n32 == 0) {
#pragma unroll
        for (int reg = 0; reg < 16; reg++) {
            int row = (reg & 3) + 8 * (reg >> 2) + 4 * half;
            lpart[(size_t)bh * P_ + p0 + wv * 32 + row] = lrow[reg];
        }
    }

    // RAW partial-O writeback via per-wave LDS transpose (Ps[wv] as [32][36] f32).
    float* Psf = (float*)&Ps[wv][0][0];
#pragma unroll
    for (int nt = 0; nt < 2; nt++) {
#pragma unroll
        for (int reg = 0; reg < 16; reg++) {
            int row = (reg & 3) + 8 * (reg >> 2) + 4 * half;
            Psf[row * 36 + n32] = oacc[nt][reg];
        }
        // In-wave DS ordering: writes above complete before reads below.
#pragma unroll
        for (int i = 0; i < 4; i++) {
            int ql = i * 8 + (lane >> 3);
            int c4 = lane & 7;
            float4 v = *(const float4*)&Psf[ql * 36 + c4 * 4];
            *(float4*)(opart + ((size_t)bh * P_ + p0 + wv * 32 + ql) * HD_ + nt * 32 + c4 * 4) = v;
        }
    }
}

// ===========================================================================
// Kernel 3: LayerNorm over D=768, fused split-combine: v = (o0+o1)/(l0+l1).
// (unchanged — sole owner of normalization)
// ===========================================================================
__global__ __launch_bounds__(256) void ln_o(const float* __restrict__ o0,
                                            const float* __restrict__ o1,
                                            const float* __restrict__ l0,
                                            const float* __restrict__ l1,
                                            ushort* __restrict__ lnb,
                                            const float* __restrict__ osc,
                                            const float* __restrict__ ob) {
    __shared__ float red[4];
    __shared__ float red2[4];
    const int row = blockIdx.x;          // b*P + p
    const int b   = row >> 11;
    const int p   = row & (P_ - 1);
    const int tid = threadIdx.x;

    auto src = [&](int d) {
        int h = d >> 6;
        size_t lr  = (size_t)(b * H_ + h) * P_ + p;
        size_t idx = lr * HD_ + (d & 63);
        return (o0[idx] + o1[idx]) / (l0[lr] + l1[lr]);
    };
    float v0 = src(tid);
    float v1 = src(tid + 256);
    float v2 = src(tid + 512);
    float s = v0 + v1 + v2;
#pragma unroll
    for (int o = 32; o > 0; o >>= 1) s += __shfl_xor(s, o, 64);
    if ((tid & 63) == 0) red[tid >> 6] = s;
    __syncthreads();
    float mean = (red[0] + red[1] + red[2] + red[3]) * (1.0f / 768.0f);
    float d0 = v0 - mean, d1 = v1 - mean, d2 = v2 - mean;
    float sq = d0 * d0 + d1 * d1 + d2 * d2;
#pragma unroll
    for (int o = 32; o > 0; o >>= 1) sq += __shfl_xor(sq, o, 64);
    if ((tid & 63) == 0) red2[tid >> 6] = sq;
    __syncthreads();
    float var = (red2[0] + red2[1] + red2[2] + red2[3]) * (1.0f / 768.0f);
    float inv = rsqrtf(var + 1e-6f);
    const size_t base = (size_t)row * D_;
    lnb[base + tid]       = f2bf(d0 * inv * osc[tid]       + ob[tid]);
    lnb[base + tid + 256] = f2bf(d1 * inv * osc[tid + 256] + ob[tid + 256]);
    lnb[base + tid + 512] = f2bf(d2 * inv * osc[tid + 512] + ob[tid + 512]);
}

// ===========================================================================
// Kernel 4: out = ln_buf(bf16) @ W_out + b_out. 64x64 tile. (unchanged R14)
// ===========================================================================
__global__ __launch_bounds__(256) void gemm_out_mfma(
        const ushort* __restrict__ a, const float* __restrict__ w,
        const float* __restrict__ bias, float* __restrict__ out) {
    __shared__ __align__(16) ushort As[64][40];
    __shared__ __align__(16) ushort Bs[64][40];

    const int tid  = threadIdx.x;
    const int lane = tid & 63;
    const int wv   = tid >> 6;
    const int quad = lane >> 4;
    const int col  = lane & 15;
    const int wr   = (wv >> 1) * 32;
    const int wc   = (wv & 1) * 32;
    const int rowBase = blockIdx.y * 64;
    const int colBase = blockIdx.x * 64;

    const int am  = tid >> 2, ac8 = tid & 3;
    const int nB  = tid & 63, kq = tid >> 6;

    uint4 apre;
    float bpre[8];
    auto load_tile = [&](int kt) {
        const int k0 = kt * 32;
        apre = *(const uint4*)(a + (size_t)(rowBase + am) * D_ + k0 + ac8 * 8);
#pragma unroll
        for (int j = 0; j < 8; j++)
            bpre[j] = w[(size_t)(k0 + kq * 8 + j) * D_ + colBase + nB];
    };

    f32x4 acc[2][2];
#pragma unroll
    for (int i = 0; i < 2; i++)
#pragma unroll
        for (int j = 0; j < 2; j++) acc[i][j] = (f32x4){0.f, 0.f, 0.f, 0.f};

    load_tile(0);
    const int NT = D_ / 32;
    for (int kt = 0; kt < NT; kt++) {
        __syncthreads();
        *(uint4*)&As[am][ac8 * 8] = apre;
        {
            ushort us[8];
#pragma unroll
            for (int j = 0; j < 8; j++) us[j] = f2bf(bpre[j]);
            *(short8*)&Bs[nB][kq * 8] = *(short8*)&us[0];
        }
        __syncthreads();
        if (kt + 1 < NT) load_tile(kt + 1);

        short8 af[2], bf[2];
#pragma unroll
        for (int mt = 0; mt < 2; mt++) af[mt] = *(const short8*)&As[wr + mt * 16 + col][quad * 8];
#pragma unroll
        for (int nt = 0; nt < 2; nt++) bf[nt] = *(const short8*)&Bs[wc + nt * 16 + col][quad * 8];
#pragma unroll
        for (int mt = 0; mt < 2; mt++)
#pragma unroll
            for (int nt = 0; nt < 2; nt++)
                acc[mt][nt] = __builtin_amdgcn_mfma_f32_16x16x32_bf16(af[mt], bf[nt], acc[mt][nt], 0, 0, 0);
    }

    float b2[2];
#pragma unroll
    for (int nt = 0; nt < 2; nt++) b2[nt] = bias[colBase + wc + nt * 16 + col];
#pragma unroll
    for (int mt = 0; mt < 2; mt++) {
#pragma unroll
        for (int r = 0; r < 4; r++) {
            int m = rowBase + wr + mt * 16 + quad * 4 + r;
            float* dst = out + (size_t)m * D_ + colBase + wc;
#pragma unroll
            for (int nt = 0; nt < 2; nt++)
                dst[nt * 16 + col] = acc[mt][nt][r] + b2[nt];
        }
    }
}

// ---------------------------------------------------------------------------
extern "C" void kernel_launch(void* const* d_in, const int* in_sizes, int n_in,
                              void* d_out, int out_size, void* d_ws, size_t ws_size,
                              hipStream_t stream) {
    const float* x    = (const float*)d_in[0];
    const float* Wqkv = (const float*)d_in[1];
    const float* qs   = (const float*)d_in[2];
    const float* qb   = (const float*)d_in[3];
    const float* ks   = (const float*)d_in[4];
    const float* kb   = (const float*)d_in[5];
    const float* osc  = (const float*)d_in[6];
    const float* ob   = (const float*)d_in[7];
    const float* Wout = (const float*)d_in[8];
    const float* bout = (const float*)d_in[9];
    float* out = (float*)d_out;

    // Workspace (31.9 MB): qkv bf16 18.9MB | opart0 fp32 12.6MB | l0,l1 0.4MB
    // d_out holds opart1 during attention (fp32, exactly B*P*D elements).
    ushort* qkv    = (ushort*)d_ws;
    float*  opart0 = (float*)(qkv + (size_t)3 * B_ * H_ * P_ * HD_);
    float*  l0     = opart0 + (size_t)B_ * H_ * P_ * HD_;
    float*  l1     = l0 + (size_t)B_ * H_ * P_;
    float*  opart1 = out;
    ushort* ln_buf = qkv;   // overlays dead q-region after attention

    gemm_qkv_mfma<<<dim3(N1_ / 128, M_ / 128), 512, 0, stream>>>(x, Wqkv, qs, qb, ks, kb, qkv);
    attn_split<<<dim3(P_ / 128, B_ * H_, 2), 256, 0, stream>>>(qkv, opart0, opart1, l0, l1);
    ln_o<<<dim3(M_), 256, 0, stream>>>(opart0, opart1, l0, l1, ln_buf, osc, ob);
    gemm_out_mfma<<<dim3(D_ / 64, M_ / 64), 256, 0, stream>>>(ln_buf, Wout, bout, out);
}